// Round 7
// baseline (136.758 us; speedup 1.0000x reference)
//
#include <hip/hip_runtime.h>

#define IN_DIM 128
#define OUT_DIM 128

typedef __attribute__((ext_vector_type(8))) short short8v;   // 8 bf16 = 4 VGPRs
typedef __attribute__((ext_vector_type(4))) float float4v;
typedef __attribute__((ext_vector_type(4))) unsigned int uint4v;
typedef __attribute__((ext_vector_type(2))) unsigned int uint2v;

__device__ __forceinline__ ushort f2bf(float f) {
    unsigned int u = __builtin_bit_cast(unsigned int, f);
    unsigned int r = (u + 0x7fffu + ((u >> 16) & 1u)) >> 16;   // RNE
    return (ushort)r;
}

__device__ __forceinline__ unsigned int pk2bf(float x, float y) {
#if __has_builtin(__builtin_amdgcn_cvt_pk_bf16_f32)
    typedef __attribute__((ext_vector_type(2))) __bf16 bf2;
    bf2 r = __builtin_amdgcn_cvt_pk_bf16_f32(x, y);
    return __builtin_bit_cast(unsigned int, r);
#else
    return (unsigned int)f2bf(x) | ((unsigned int)f2bf(y) << 16);
#endif
}

// ---------------- Kernel 0: prep (Wt only, 16 blocks) ----------------
// Wt[n][k] = bf16(W[k][n]), row stride 136. Coalesced fp32 reads, b32 stores.
__global__ __launch_bounds__(256) void prep_kernel(const float* __restrict__ W,
                                                   ushort* __restrict__ Wt) {
    int k0 = blockIdx.x * 8;
    int n = threadIdx.x & 127;
    int half = threadIdx.x >> 7;
#pragma unroll
    for (int kp = 0; kp < 2; ++kp) {
        int k = k0 + (half * 2 + kp) * 2;
        float v0 = W[k * 128 + n];          // coalesced across lanes
        float v1 = W[(k + 1) * 128 + n];
        *(unsigned int*)&Wt[n * 136 + k] = pk2bf(v0, v1);
    }
}

// ---------------- Kernel 1: T(biased-uint8, per-row scale) = H @ W, + rp tail ----------------
// Blocks [0, nb_gemm): 64-row x 128-col tile, K=128 unrolled (proven core).
// Epilogue: per-row absmax (shfl_xor 16/32 over quarter-lanes), quantize row
// to BIASED uint8 (q+128) with scale S[row] = rowmax/127 -> fetch-cheap
// scatter gather AND single-instruction v_cvt_f32_ubyte decode.
// Blocks [nb_gemm, ...): row_ptr[n] = lower_bound(edst, n) (overlaps gemm).
__global__ __launch_bounds__(256) void gemm_kernel(const float* __restrict__ H,
                                                   const ushort* __restrict__ Wt_g,
                                                   unsigned char* __restrict__ T8,
                                                   float* __restrict__ S, int M,
                                                   const int* __restrict__ edst,
                                                   int* __restrict__ rp,
                                                   int E, int nb_gemm) {
    __shared__ ushort Ws[128 * 136];   // 34816 B

    const int t = threadIdx.x;

    if (blockIdx.x >= nb_gemm) {       // rp tail blocks (block-uniform branch)
        int n = (blockIdx.x - nb_gemm) * 256 + t;
        if (n <= M) {
            int lo = 0, hi = E;
            while (lo < hi) {
                int mid = (lo + hi) >> 1;
                if (edst[mid] < n) lo = mid + 1; else hi = mid;
            }
            rp[n] = lo;
        }
        return;
    }

    const int row0 = blockIdx.x * 64;

#pragma unroll
    for (int f = t; f < 2176; f += 256)
        ((short8v*)Ws)[f] = ((const short8v*)Wt_g)[f];

    const int w = t >> 6;
    const int l = t & 63;
    const int m16 = l & 15;
    const int kq = (l >> 4) * 8;
    const int gr = row0 + w * 16 + m16;

    float4 h[8];
    if (gr < M) {
#pragma unroll
        for (int ks = 0; ks < 4; ++ks) {
            h[ks * 2]     = *(const float4*)&H[gr * 128 + ks * 32 + kq];
            h[ks * 2 + 1] = *(const float4*)&H[gr * 128 + ks * 32 + kq + 4];
        }
    } else {
#pragma unroll
        for (int i = 0; i < 8; ++i) h[i] = make_float4(0.f, 0.f, 0.f, 0.f);
    }

    short8v bfrag[4];
#pragma unroll
    for (int ks = 0; ks < 4; ++ks) {
        uint4v u;
        u[0] = pk2bf(h[ks * 2].x, h[ks * 2].y);
        u[1] = pk2bf(h[ks * 2].z, h[ks * 2].w);
        u[2] = pk2bf(h[ks * 2 + 1].x, h[ks * 2 + 1].y);
        u[3] = pk2bf(h[ks * 2 + 1].z, h[ks * 2 + 1].w);
        bfrag[ks] = __builtin_bit_cast(short8v, u);
    }

    __syncthreads();   // Ws ready

    float4v acc[8];
#pragma unroll
    for (int nt = 0; nt < 8; ++nt) acc[nt] = (float4v){0.f, 0.f, 0.f, 0.f};

#pragma unroll
    for (int ks = 0; ks < 4; ++ks) {
#pragma unroll
        for (int nt = 0; nt < 8; ++nt) {
            short8v afrag = *(const short8v*)&Ws[(nt * 16 + m16) * 136 + ks * 32 + kq];
            acc[nt] = __builtin_amdgcn_mfma_f32_16x16x32_bf16(afrag, bfrag[ks], acc[nt], 0, 0, 0);
        }
    }

    // Per-row absmax across this lane's 32 cols, then across the 4 quarter-
    // lanes sharing row gr (l, l^16, l^32, l^48).
    float mx = 0.f;
#pragma unroll
    for (int nt = 0; nt < 8; ++nt) {
#pragma unroll
        for (int k = 0; k < 4; ++k) mx = fmaxf(mx, fabsf(acc[nt][k]));
    }
    mx = fmaxf(mx, __shfl_xor(mx, 16));
    mx = fmaxf(mx, __shfl_xor(mx, 32));

    const float inv = 127.0f / fmaxf(mx, 1e-20f);

    if (gr < M) {
        const int qd = l >> 4;
        if (qd == 0) S[gr] = mx * (1.0f / 127.0f);
#pragma unroll
        for (int nt = 0; nt < 8; ++nt) {
            unsigned int p = 0;
#pragma unroll
            for (int k = 0; k < 4; ++k) {
                int qi = (int)__builtin_rintf(acc[nt][k] * inv);
                qi = qi > 127 ? 127 : (qi < -127 ? -127 : qi);
                p |= ((unsigned int)(qi + 128) & 0xffu) << (k * 8);   // biased
            }
            *(unsigned int*)&T8[gr * 128 + nt * 16 + qd * 4] = p;
        }
    }
}

// ---------------- Kernel 2: out[n][:] = b + sum_{e} w_e*S[src]*(T8[src][:]-128) ----------------
// One wave per node, EDGE-QUAD structure: lane owns 8 cols (one dwordx2 of a
// row). Four 16-lane groups each cover a full 128-B row -> one VMEM retires
// 4 edges. Per 16-edge batch: 8 shfl (metadata select, ds_bpermute) + 4
// dwordx2 gathers + 68 decode VALU. All (up to 4) batches of a 64-edge chunk
// are issued as STATIC straight-line code with uniform nb-guards -> the
// chunk's entire gather set is in flight before any decode (one latency
// exposure per chunk, was four). Pad edges carry ws=0 (correct, row-0
// gathers are L2-hot). Cross-quarter combine: shfl_xor 16/32 per wave.
#define ISSUE_BATCH(J, SQ, WS, V)                                              \
    {                                                                          \
        _Pragma("unroll")                                                      \
        for (int p = 0; p < 4; ++p) {                                          \
            const int sl = (J) + p * 4 + quarter;                              \
            SQ[p] = __shfl(srcl, sl);                                          \
            WS[p] = __shfl(wsl, sl);                                           \
        }                                                                      \
        _Pragma("unroll")                                                      \
        for (int p = 0; p < 4; ++p)                                            \
            V[p] = *(const uint2v*)(T8 + ((unsigned int)SQ[p] * 128u + colb)); \
    }

#define DECODE_BATCH(WS, V)                                                    \
    {                                                                          \
        _Pragma("unroll")                                                      \
        for (int p = 0; p < 4; ++p) {                                          \
            const unsigned int x = V[p][0];                                    \
            const unsigned int y = V[p][1];                                    \
            const float w = WS[p];                                             \
            B  += w;                                                           \
            a0 = fmaf((float)(x & 0xffu), w, a0);                              \
            a1 = fmaf((float)((x >> 8) & 0xffu), w, a1);                       \
            a2 = fmaf((float)((x >> 16) & 0xffu), w, a2);                      \
            a3 = fmaf((float)(x >> 24), w, a3);                                \
            a4 = fmaf((float)(y & 0xffu), w, a4);                              \
            a5 = fmaf((float)((y >> 8) & 0xffu), w, a5);                       \
            a6 = fmaf((float)((y >> 16) & 0xffu), w, a6);                      \
            a7 = fmaf((float)(y >> 24), w, a7);                                \
        }                                                                      \
    }

__global__ __launch_bounds__(256) void scatter_kernel(const unsigned char* __restrict__ T8,
                                                      const float* __restrict__ S,
                                                      const int* __restrict__ esrc,
                                                      const float* __restrict__ ew,
                                                      const int* __restrict__ rp,
                                                      const float* __restrict__ b,
                                                      float* __restrict__ out) {
    const int node = blockIdx.x * 4 + (threadIdx.x >> 6);
    const int lane = threadIdx.x & 63;
    const int quarter = lane >> 4;                    // which edge of each quad
    const unsigned int colb = (lane & 15u) * 8u;      // byte (=col) offset in row

    const int s = __builtin_amdgcn_readfirstlane(rp[node]);
    const int e = __builtin_amdgcn_readfirstlane(rp[node + 1]);

    float a0 = 0.f, a1 = 0.f, a2 = 0.f, a3 = 0.f;
    float a4 = 0.f, a5 = 0.f, a6 = 0.f, a7 = 0.f;
    float B = 0.f;              // sum of ws over this lane's edges

    for (int c = s; c < e; c += 64) {
        const int idx = c + lane;
        int srcl = 0;
        float wl = 0.f;
        if (idx < e) { srcl = esrc[idx]; wl = ew[idx]; }   // coalesced; pad w=0
        const float wsl = wl * S[srcl];                    // vector-pipe gather
        int nn = e - c;
        if (nn > 64) nn = 64;
        const int nb = (nn + 15) >> 4;   // 1..4 sixteen-edge batches (uniform)

        int   sq0[4], sq1[4], sq2[4], sq3[4];
        float ws0[4], ws1[4], ws2[4], ws3[4];
        uint2v v0[4], v1[4], v2[4], v3[4];

        ISSUE_BATCH(0, sq0, ws0, v0);
        if (nb > 1) ISSUE_BATCH(16, sq1, ws1, v1);
        if (nb > 2) ISSUE_BATCH(32, sq2, ws2, v2);
        if (nb > 3) ISSUE_BATCH(48, sq3, ws3, v3);

        DECODE_BATCH(ws0, v0);
        if (nb > 1) DECODE_BATCH(ws1, v1);
        if (nb > 2) DECODE_BATCH(ws2, v2);
        if (nb > 3) DECODE_BATCH(ws3, v3);
    }

    // Combine the 4 quarter-groups (lanes l, l^16, l^32, l^48 share cols).
    a0 += __shfl_xor(a0, 16); a0 += __shfl_xor(a0, 32);
    a1 += __shfl_xor(a1, 16); a1 += __shfl_xor(a1, 32);
    a2 += __shfl_xor(a2, 16); a2 += __shfl_xor(a2, 32);
    a3 += __shfl_xor(a3, 16); a3 += __shfl_xor(a3, 32);
    a4 += __shfl_xor(a4, 16); a4 += __shfl_xor(a4, 32);
    a5 += __shfl_xor(a5, 16); a5 += __shfl_xor(a5, 32);
    a6 += __shfl_xor(a6, 16); a6 += __shfl_xor(a6, 32);
    a7 += __shfl_xor(a7, 16); a7 += __shfl_xor(a7, 32);
    B  += __shfl_xor(B, 16);  B  += __shfl_xor(B, 32);

    if (quarter == 0) {
        const int col = (lane & 15) * 8;
        const float4 b0 = *(const float4*)&b[col];
        const float4 b1 = *(const float4*)&b[col + 4];
        float4 o0, o1;
        o0.x = fmaf(-128.0f, B, a0) + b0.x;
        o0.y = fmaf(-128.0f, B, a1) + b0.y;
        o0.z = fmaf(-128.0f, B, a2) + b0.z;
        o0.w = fmaf(-128.0f, B, a3) + b0.w;
        o1.x = fmaf(-128.0f, B, a4) + b1.x;
        o1.y = fmaf(-128.0f, B, a5) + b1.y;
        o1.z = fmaf(-128.0f, B, a6) + b1.z;
        o1.w = fmaf(-128.0f, B, a7) + b1.w;
        *(float4*)&out[node * 128 + col]     = o0;
        *(float4*)&out[node * 128 + col + 4] = o1;
    }
}

extern "C" void kernel_launch(void* const* d_in, const int* in_sizes, int n_in,
                              void* d_out, int out_size, void* d_ws, size_t ws_size,
                              hipStream_t stream) {
    const float* H    = (const float*)d_in[0];
    const int*   esrc = (const int*)d_in[1];
    const int*   edst = (const int*)d_in[2];
    const float* ew   = (const float*)d_in[3];
    const float* W    = (const float*)d_in[4];
    const float* b    = (const float*)d_in[5];
    float* out = (float*)d_out;

    const int M = in_sizes[0] / IN_DIM;   // 50000 nodes
    const int E = in_sizes[1];            // 1,600,000 edges

    // Workspace layout (~6.8 MB)
    unsigned char* T8 = (unsigned char*)d_ws;                       // M*128 B (biased uint8)
    size_t off = (size_t)M * 128;
    float* S  = (float*)((char*)d_ws + off);                        // M floats
    off += (size_t)M * 4;
    ushort* Wt = (ushort*)((char*)d_ws + off);                      // 128*136*2 B
    off += 128 * 136 * 2;
    int* rp = (int*)((char*)d_ws + off);                            // (M+1) ints

    // Wt transpose (16 blocks)
    prep_kernel<<<16, 256, 0, stream>>>(W, Wt);

    // gemm (biased-uint8 output + per-row scale) + rp tail blocks
    const int nb_gemm = (M + 63) / 64;         // 782
    const int nb_rp   = (M + 1 + 255) / 256;   // 196
    gemm_kernel<<<nb_gemm + nb_rp, 256, 0, stream>>>(H, Wt, T8, S, M, edst, rp, E, nb_gemm);

    scatter_kernel<<<(M + 3) / 4, 256, 0, stream>>>(T8, S, esrc, ew, rp, b, out);
}